// Round 4
// baseline (1091.871 us; speedup 1.0000x reference)
//
#include <hip/hip_runtime.h>
#include <math.h>

#define D 512
#define W_GRP 1536
#define T_ROWS 30000
#define T_PAD 30720
#define NCH 240      // col-chunks of 128 (2 tiles of 64 per block)
#define NRB 6        // row-blocks of 256

typedef unsigned short ushort_t;
typedef short v8s __attribute__((ext_vector_type(8)));
typedef float v4f __attribute__((ext_vector_type(4)));

__device__ __forceinline__ ushort_t rne_bf16(float x) {
    unsigned int u = __float_as_uint(x);
    u = (u + 0x7fffu + ((u >> 16) & 1u)) >> 16;
    return (ushort_t)u;
}
__device__ __forceinline__ float bf16_to_f(ushort_t h) {
    return __uint_as_float(((unsigned int)h) << 16);
}

__device__ __forceinline__ void top5_insert(float (&v)[5], int (&ix)[5], float s, int gi) {
    if (s <= v[4]) return;
    v[4] = s; ix[4] = gi;
    #pragma unroll
    for (int q = 4; q > 0; --q) {
        if (v[q] > v[q-1]) {
            float tv = v[q]; v[q] = v[q-1]; v[q-1] = tv;
            int ti = ix[q]; ix[q] = ix[q-1]; ix[q-1] = ti;
        } else break;
    }
}

// ---------------- Kernel A: group-average + L2-normalize -> a_hi/a_lo bf16
__global__ __launch_bounds__(256) void avg_norm_kernel(const float* __restrict__ x,
                                                       ushort_t* __restrict__ ah,
                                                       ushort_t* __restrict__ al) {
    const int g = blockIdx.x, tid = threadIdx.x;
    const float* base = x + (size_t)g * 64 * D + tid * 2;
    float s0 = 0.f, s1 = 0.f;
    #pragma unroll 8
    for (int r = 0; r < 64; ++r) {
        const float2 v = *(const float2*)(base + (size_t)r * D);
        s0 += v.x; s1 += v.y;
    }
    s0 *= (1.f / 64.f); s1 *= (1.f / 64.f);
    float ss = s0 * s0 + s1 * s1;
    for (int off = 32; off > 0; off >>= 1) ss += __shfl_down(ss, off, 64);
    __shared__ float red[4];
    __shared__ float scale_s;
    const int lane = tid & 63, wid = tid >> 6;
    if (lane == 0) red[wid] = ss;
    __syncthreads();
    if (tid == 0) {
        float tot = red[0] + red[1] + red[2] + red[3];
        scale_s = 1.f / fmaxf(sqrtf(tot), 1e-8f);
    }
    __syncthreads();
    const float sc = scale_s;
    const float v0 = s0 * sc, v1 = s1 * sc;
    const ushort_t h0 = rne_bf16(v0), h1 = rne_bf16(v1);
    const ushort_t l0 = rne_bf16(v0 - bf16_to_f(h0));
    const ushort_t l1 = rne_bf16(v1 - bf16_to_f(h1));
    *(unsigned int*)(ah + (size_t)g * D + tid * 2) = (unsigned int)h0 | ((unsigned int)h1 << 16);
    *(unsigned int*)(al + (size_t)g * D + tid * 2) = (unsigned int)l0 | ((unsigned int)l1 << 16);
}

// ---------------- Kernel B: t -> hi/lo bf16 + inverse row norms (float4 loads)
__global__ __launch_bounds__(256) void tconv_kernel(const float* __restrict__ t,
                                                    ushort_t* __restrict__ th,
                                                    ushort_t* __restrict__ tl,
                                                    float* __restrict__ invt) {
    const int wid = threadIdx.x >> 6, lane = threadIdx.x & 63;
    const int row = blockIdx.x * 4 + wid;
    if (row >= T_ROWS) return;
    const float* p = t + (size_t)row * D;
    float ss = 0.f;
    #pragma unroll
    for (int m = 0; m < 2; ++m) {
        const int c = lane * 4 + m * 256;
        const float4 v = *(const float4*)(p + c);
        ss += v.x * v.x + v.y * v.y + v.z * v.z + v.w * v.w;
        const ushort_t h0 = rne_bf16(v.x), h1 = rne_bf16(v.y), h2 = rne_bf16(v.z), h3 = rne_bf16(v.w);
        const ushort_t l0 = rne_bf16(v.x - bf16_to_f(h0));
        const ushort_t l1 = rne_bf16(v.y - bf16_to_f(h1));
        const ushort_t l2 = rne_bf16(v.z - bf16_to_f(h2));
        const ushort_t l3 = rne_bf16(v.w - bf16_to_f(h3));
        uint2 hp, lp;
        hp.x = (unsigned int)h0 | ((unsigned int)h1 << 16);
        hp.y = (unsigned int)h2 | ((unsigned int)h3 << 16);
        lp.x = (unsigned int)l0 | ((unsigned int)l1 << 16);
        lp.y = (unsigned int)l2 | ((unsigned int)l3 << 16);
        *(uint2*)(th + (size_t)row * D + c) = hp;
        *(uint2*)(tl + (size_t)row * D + c) = lp;
    }
    for (int off = 32; off > 0; off >>= 1) ss += __shfl_down(ss, off, 64);
    if (lane == 0) invt[row] = 1.f / fmaxf(sqrtf(ss), 1e-8f);
}

// ---------------- Kernel C: MFMA scores, LDS-staged B, fused top-5 (unchanged)
union SMemC {
    ushort_t stage[2][2][256][8];   // [buf][hi/lo][unit][8 shorts] = 16 KB
    float epi[4][64][33];           // per-wave 64x32(+pad) score slab = 33.8 KB
};

__global__ __launch_bounds__(256, 2) void score_topk_kernel(
        const ushort_t* __restrict__ ah, const ushort_t* __restrict__ al,
        const ushort_t* __restrict__ th, const ushort_t* __restrict__ tl,
        const float* __restrict__ invt,
        float* __restrict__ cand_val, int* __restrict__ cand_idx) {
    __shared__ SMemC sm;
    const int tid = threadIdx.x;
    const int w = tid >> 6, lane = tid & 63;
    const int quad = lane >> 4, nid = lane & 15;
    const int cc = blockIdx.x, rb = blockIdx.y;
    const int wrow0 = rb * 256 + w * 64;

    const ushort_t* aph[4];
    const ushort_t* apl[4];
    #pragma unroll
    for (int fi = 0; fi < 4; ++fi) {
        const size_t ro = (size_t)(wrow0 + fi * 16 + nid) * D + quad * 8;
        aph[fi] = ah + ro;
        apl[fi] = al + ro;
    }

    const int col_s = tid & 63, seg_s = tid >> 6;

    float tv[5]; int tix[5];
    #pragma unroll
    for (int s = 0; s < 5; ++s) { tv[s] = -INFINITY; tix[s] = 0; }

    for (int ct = 0; ct < 2; ++ct) {
        const int cb64 = cc * 128 + ct * 64;
        const ushort_t* gth = th + (size_t)(cb64 + col_s) * D + seg_s * 8;
        const ushort_t* gtl = tl + (size_t)(cb64 + col_s) * D + seg_s * 8;

        v4f acc[4][4];
        #pragma unroll
        for (int fi = 0; fi < 4; ++fi)
            #pragma unroll
            for (int fj = 0; fj < 4; ++fj) acc[fi][fj] = (v4f){0.f, 0.f, 0.f, 0.f};

        {
            const v8s h0 = *(const v8s*)gth;
            const v8s l0 = *(const v8s*)gtl;
            *(v8s*)&sm.stage[0][0][tid][0] = h0;
            *(v8s*)&sm.stage[0][1][tid][0] = l0;
        }
        __syncthreads();

        for (int kt = 0; kt < 16; ++kt) {
            const int kb = kt * 32;
            const int cur = kt & 1, nxt = cur ^ 1;
            v8s nh, nl;
            if (kt < 15) {
                nh = *(const v8s*)(gth + kb + 32);
                nl = *(const v8s*)(gtl + kb + 32);
            }
            v8s fah[4], fal[4];
            #pragma unroll
            for (int fi = 0; fi < 4; ++fi) {
                fah[fi] = *(const v8s*)(aph[fi] + kb);
                fal[fi] = *(const v8s*)(apl[fi] + kb);
            }
            #pragma unroll
            for (int fj = 0; fj < 4; ++fj) {
                const int u = quad * 64 + fj * 16 + nid;
                const v8s bh = *(const v8s*)&sm.stage[cur][0][u][0];
                const v8s bl = *(const v8s*)&sm.stage[cur][1][u][0];
                #pragma unroll
                for (int fi = 0; fi < 4; ++fi) {
                    acc[fi][fj] = __builtin_amdgcn_mfma_f32_16x16x32_bf16(fah[fi], bh, acc[fi][fj], 0, 0, 0);
                    acc[fi][fj] = __builtin_amdgcn_mfma_f32_16x16x32_bf16(fal[fi], bh, acc[fi][fj], 0, 0, 0);
                    acc[fi][fj] = __builtin_amdgcn_mfma_f32_16x16x32_bf16(fah[fi], bl, acc[fi][fj], 0, 0, 0);
                }
            }
            if (kt < 15) {
                *(v8s*)&sm.stage[nxt][0][tid][0] = nh;
                *(v8s*)&sm.stage[nxt][1][tid][0] = nl;
            }
            __syncthreads();
        }

        #pragma unroll
        for (int h = 0; h < 2; ++h) {
            #pragma unroll
            for (int fjh = 0; fjh < 2; ++fjh) {
                const int fj = h * 2 + fjh;
                const int gcol = cb64 + fj * 16 + nid;
                const bool ok = gcol < T_ROWS;
                const float it = ok ? invt[gcol] : 0.f;
                #pragma unroll
                for (int fi = 0; fi < 4; ++fi)
                    #pragma unroll
                    for (int r = 0; r < 4; ++r) {
                        const int row = fi * 16 + quad * 4 + r;
                        sm.epi[w][row][fjh * 16 + nid] = ok ? acc[fi][fj][r] * it : -INFINITY;
                    }
            }
            __syncthreads();
            #pragma unroll 8
            for (int c = 0; c < 32; ++c)
                top5_insert(tv, tix, sm.epi[w][lane][c], cb64 + h * 32 + c);
            __syncthreads();
        }
    }

    const int grow = rb * 256 + tid;
    #pragma unroll
    for (int s = 0; s < 5; ++s) {
        cand_val[((size_t)grow * NCH + cc) * 5 + s] = tv[s];
        cand_idx[((size_t)grow * NCH + cc) * 5 + s] = tix[s];
    }
}

// ---------------- Kernel D: wave-per-row merge of per-chunk candidates
// lane l scans entries l, l+64, ... (coalesced), then 6-step shfl_xor butterfly.
__global__ __launch_bounds__(256) void merge_chunks_kernel(const float* __restrict__ cand_val,
                                                           const int* __restrict__ cand_idx,
                                                           int* __restrict__ topk) {
    const int w = threadIdx.x >> 6, lane = threadIdx.x & 63;
    const int row = blockIdx.x * 4 + w;
    const float* cv = cand_val + (size_t)row * (NCH * 5);
    const int*   ci = cand_idx + (size_t)row * (NCH * 5);
    float v[5]; int ix[5];
    #pragma unroll
    for (int s = 0; s < 5; ++s) { v[s] = -INFINITY; ix[s] = 0; }
    for (int c = lane; c < NCH * 5; c += 64)
        top5_insert(v, ix, cv[c], ci[c]);
    #pragma unroll
    for (int m = 1; m < 64; m <<= 1) {
        float ov[5]; int oix[5];
        #pragma unroll
        for (int s = 0; s < 5; ++s) {
            ov[s]  = __shfl_xor(v[s], m, 64);
            oix[s] = __shfl_xor(ix[s], m, 64);
        }
        #pragma unroll
        for (int s = 0; s < 5; ++s) {
            if (ov[s] <= v[4]) break;   // both lists sorted descending
            top5_insert(v, ix, ov[s], oix[s]);
        }
    }
    if (lane == 0) {
        #pragma unroll
        for (int s = 0; s < 5; ++s) topk[row * 5 + s] = ix[s];
    }
}

// ---------------- Kernel E: gather top-5, average, out = avg @ W^T + b
#define RPB 8
__global__ __launch_bounds__(256) void out_kernel(const float* __restrict__ st,
                                                  const float* __restrict__ W,
                                                  const float* __restrict__ b,
                                                  const int* __restrict__ topk,
                                                  float* __restrict__ out) {
    __shared__ float avgT[D][12];
    const int tid = threadIdx.x;
    const int rb = blockIdx.x;
    for (int r = 0; r < RPB; ++r) {
        const int grow = rb * RPB + r;
        const int* id = &topk[grow * 5];
        const int i0 = id[0], i1 = id[1], i2 = id[2], i3 = id[3], i4 = id[4];
        #pragma unroll
        for (int cw = 0; cw < 2; ++cw) {
            const int c = tid + cw * 256;
            const float s = (st[(size_t)i0 * D + c] + st[(size_t)i1 * D + c] +
                             st[(size_t)i2 * D + c] + st[(size_t)i3 * D + c] +
                             st[(size_t)i4 * D + c]) * 0.2f;
            avgT[c][r] = s;
        }
    }
    __syncthreads();
    const int j0 = tid * 2;
    float acc0[RPB], acc1[RPB];
    #pragma unroll
    for (int r = 0; r < RPB; ++r) { acc0[r] = 0.f; acc1[r] = 0.f; }
    for (int i = 0; i < D; i += 4) {
        const float4 w0 = *(const float4*)&W[(size_t)j0 * D + i];
        const float4 w1 = *(const float4*)&W[(size_t)(j0 + 1) * D + i];
        const float wa[4] = {w0.x, w0.y, w0.z, w0.w};
        const float wb[4] = {w1.x, w1.y, w1.z, w1.w};
        #pragma unroll
        for (int d = 0; d < 4; ++d) {
            #pragma unroll
            for (int r = 0; r < RPB; ++r) {
                const float av = avgT[i + d][r];
                acc0[r] = fmaf(av, wa[d], acc0[r]);
                acc1[r] = fmaf(av, wb[d], acc1[r]);
            }
        }
    }
    const float b0 = b[j0], b1 = b[j0 + 1];
    #pragma unroll
    for (int r = 0; r < RPB; ++r) {
        const int grow = rb * RPB + r;
        float2 o; o.x = acc0[r] + b0; o.y = acc1[r] + b1;
        *(float2*)&out[(size_t)grow * D + j0] = o;
    }
}

extern "C" void kernel_launch(void* const* d_in, const int* in_sizes, int n_in,
                              void* d_out, int out_size, void* d_ws, size_t ws_size,
                              hipStream_t stream) {
    const float* x  = (const float*)d_in[0];   // (1, 131072, 512)
    const float* st = (const float*)d_in[1];   // (30000, 512)
    const float* W  = (const float*)d_in[2];   // (512, 512)
    const float* b  = (const float*)d_in[3];   // (512,)
    float* out = (float*)d_out;                // (1536, 512)
    char* base = (char*)d_ws;

    ushort_t* th  = (ushort_t*)(base);                 // 31,457,280 B
    ushort_t* tl  = (ushort_t*)(base + 31457280);      // 31,457,280 B
    ushort_t* ah  = (ushort_t*)(base + 62914560);      // 1,572,864 B
    ushort_t* al  = (ushort_t*)(base + 64487424);      // 1,572,864 B
    float*    invt= (float*)   (base + 66060288);      // 131,072 B
    float*    cval= (float*)   (base + 66191360);      // 7,372,800 B
    int*      cidx= (int*)     (base + 73564160);      // 7,372,800 B
    int*      topk= (int*)     (base + 80936960);      // 30,720 B -> total ~81 MB

    avg_norm_kernel<<<W_GRP, 256, 0, stream>>>(x, ah, al);
    tconv_kernel<<<(T_ROWS + 3) / 4, 256, 0, stream>>>(st, th, tl, invt);
    dim3 gC(NCH, NRB);
    score_topk_kernel<<<gC, 256, 0, stream>>>(ah, al, th, tl, invt, cval, cidx);
    merge_chunks_kernel<<<W_GRP / 4, 256, 0, stream>>>(cval, cidx, topk);
    out_kernel<<<W_GRP / RPB, 256, 0, stream>>>(st, W, b, topk, out);
}